// Round 3
// baseline (79515.955 us; speedup 1.0000x reference)
//
#include <hip/hip_runtime.h>
#include <cstdint>
#include <cstddef>

#define BB 1024
#define SS 100
#define HH 256
#define CMAX 384   // max batch-chunk rows (chunks: 384, 384, 256)

// ---------------------------------------------------------------------------
// Bit-exact JAX threefry2x32
// ---------------------------------------------------------------------------
__device__ __forceinline__ unsigned rotl32(unsigned v, int r) {
  return (v << r) | (v >> (32 - r));
}

__device__ __forceinline__ void threefry2x32(unsigned k0, unsigned k1,
                                             unsigned x0, unsigned x1,
                                             unsigned& o0, unsigned& o1) {
  unsigned k2 = k0 ^ k1 ^ 0x1BD11BDAu;
  x0 += k0; x1 += k1;
#define TF_R(r) { x0 += x1; x1 = rotl32(x1, (r)); x1 ^= x0; }
  TF_R(13) TF_R(15) TF_R(26) TF_R(6)
  x0 += k1; x1 += k2 + 1u;
  TF_R(17) TF_R(29) TF_R(16) TF_R(24)
  x0 += k2; x1 += k0 + 2u;
  TF_R(13) TF_R(15) TF_R(26) TF_R(6)
  x0 += k0; x1 += k1 + 3u;
  TF_R(17) TF_R(29) TF_R(16) TF_R(24)
  x0 += k1; x1 += k2 + 4u;
  TF_R(13) TF_R(15) TF_R(26) TF_R(6)
  x0 += k2; x1 += k0 + 5u;
#undef TF_R
  o0 = x0; o1 = x1;
}

__device__ __forceinline__ double sigd(double x) {
  return 1.0 / (1.0 + exp(-x));
}

// ---------------------------------------------------------------------------
// encoder init: h = c = 0 for chunk
// ---------------------------------------------------------------------------
__global__ __launch_bounds__(256) void zero_hc(
    double* __restrict__ h, double* __restrict__ c) {
  int i = blockIdx.x * 256 + threadIdx.x;
  h[i] = 0.0;
  c[i] = 0.0;
}

// decoder init: dec_in = start, mask = 0 (chunk-local)
__global__ __launch_bounds__(256) void init_dec(
    double* __restrict__ dec_in, int* __restrict__ mask,
    const float* __restrict__ start) {
  int r = blockIdx.x, t = threadIdx.x;
  dec_in[r * HH + t] = (double)start[t];
  if (t < SS) mask[r * SS + t] = 0;
}

// ---------------------------------------------------------------------------
// xslice[r,h] = embedded[base+r, t, h]  (embedded never materialized)
// ---------------------------------------------------------------------------
__global__ __launch_bounds__(256) void embed_slice(
    const float* __restrict__ in, const float* __restrict__ w,
    const float* __restrict__ bias, double* __restrict__ xs, int t, int base) {
  int r = blockIdx.x, h = threadIdx.x;
  int b = base + r;
  int ib = (b * SS + t) * 2;
  xs[r * HH + h] = (double)in[ib] * (double)w[2 * h] +
                   (double)in[ib + 1] * (double)w[2 * h + 1] + (double)bias[h];
}

// ---------------------------------------------------------------------------
// C[m,n] = sum_k A1[m,k]W1[n,k] (+ sum_k A2[m,k]W2[n,k]) + b1[n] + b2[n]
// All math fp64; A fp64, W/bias fp32. Tile 64x64, thread 4x4, K-chunk 16.
// ---------------------------------------------------------------------------
__global__ __launch_bounds__(256) void gemm_dual(
    const double* __restrict__ A1, int lda1, const float* __restrict__ W1, int k1len,
    const double* __restrict__ A2, int lda2, const float* __restrict__ W2, int k2len,
    const float* __restrict__ bias1, const float* __restrict__ bias2,
    double* __restrict__ C, int ldc) {
  __shared__ double As[16][68];
  __shared__ double Ws[16][68];
  const int tid = threadIdx.x;
  const int tx = tid & 15, ty = tid >> 4;
  const int m0 = blockIdx.x * 64;
  const int n0 = blockIdx.y * 64;
  const int lrow = tid >> 2;          // 0..63
  const int lcol = (tid & 3) << 2;    // 0,4,8,12
  double acc[4][4] = {};

  for (int ph = 0; ph < 2; ++ph) {
    const int K = ph ? k2len : k1len;
    if (K == 0) continue;
    const double* A = ph ? A2 : A1;
    const float* W = ph ? W2 : W1;
    const int lda = ph ? lda2 : lda1;
    const double* arow = A + (size_t)(m0 + lrow) * lda;
    const float* wrow = W + (size_t)(n0 + lrow) * K;
    for (int k0 = 0; k0 < K; k0 += 16) {
      double a0 = arow[k0 + lcol + 0];
      double a1 = arow[k0 + lcol + 1];
      double a2 = arow[k0 + lcol + 2];
      double a3 = arow[k0 + lcol + 3];
      float4 wv = *(const float4*)(wrow + k0 + lcol);
      __syncthreads();
      As[lcol + 0][lrow] = a0; As[lcol + 1][lrow] = a1;
      As[lcol + 2][lrow] = a2; As[lcol + 3][lrow] = a3;
      Ws[lcol + 0][lrow] = (double)wv.x; Ws[lcol + 1][lrow] = (double)wv.y;
      Ws[lcol + 2][lrow] = (double)wv.z; Ws[lcol + 3][lrow] = (double)wv.w;
      __syncthreads();
#pragma unroll
      for (int kk = 0; kk < 16; ++kk) {
        double a[4], w[4];
#pragma unroll
        for (int i = 0; i < 4; ++i) a[i] = As[kk][ty * 4 + i];
#pragma unroll
        for (int j = 0; j < 4; ++j) w[j] = Ws[kk][tx * 4 + j];
#pragma unroll
        for (int i = 0; i < 4; ++i)
#pragma unroll
          for (int j = 0; j < 4; ++j) acc[i][j] = fma(a[i], w[j], acc[i][j]);
      }
    }
  }

#pragma unroll
  for (int i = 0; i < 4; ++i) {
    int m = m0 + ty * 4 + i;
    double* crow = C + (size_t)m * ldc + n0 + tx * 4;
#pragma unroll
    for (int j = 0; j < 4; ++j) {
      int n = n0 + tx * 4 + j;
      double bv = 0.0;
      if (bias1) bv += (double)bias1[n];
      if (bias2) bv += (double)bias2[n];
      crow[j] = acc[i][j] + bv;
    }
  }
}

// ---------------------------------------------------------------------------
// LSTM elementwise update (fp64). gates [M,4H] (i,f,g,o). Optional hout
// (encoder: enc_c + t*H, row stride S*H).
// ---------------------------------------------------------------------------
__global__ __launch_bounds__(256) void lstm_update(
    const double* __restrict__ gates, double* __restrict__ h, double* __restrict__ c,
    double* __restrict__ hout) {
  int r = blockIdx.x, u = threadIdx.x;
  const double* g = gates + (size_t)r * (4 * HH);
  double gi = g[u], gf = g[u + HH], gg = g[u + 2 * HH], go = g[u + 3 * HH];
  int idx = r * HH + u;
  double cp = c[idx];
  double cn = sigd(gf) * cp + sigd(gi) * tanh(gg);
  double hn = sigd(go) * tanh(cn);
  c[idx] = cn;
  h[idx] = hn;
  if (hout) hout[(size_t)r * (SS * HH) + u] = hn;
}

// ---------------------------------------------------------------------------
// Attention logits (chunk-local): out[r,s] = mask ? -10
//   : 10*tanh(vb + sum_h tanh(ref[r,s,h] + q[r,h]) * v[h])
// One wave per (r,s) row; masked rows skip the ref read.
// ---------------------------------------------------------------------------
__global__ __launch_bounds__(256) void attn_logits(
    const double* __restrict__ refp, const double* __restrict__ q,
    const float* __restrict__ vw, const float* __restrict__ vb,
    const int* __restrict__ mask, double* __restrict__ out) {
  int w = blockIdx.x * 4 + (threadIdx.x >> 6);  // (r,s) flat, < M*SS
  int l = threadIdx.x & 63;
  if (mask[w]) {
    if (l == 0) out[w] = -10.0;   // 10*tanh(-100000) == -10 exactly (fp64)
    return;
  }
  int r = w / SS;
  const double* rp = refp + (size_t)w * HH + l * 4;
  const double* qv = q + (size_t)r * HH + l * 4;
  double p = 0.0;
#pragma unroll
  for (int j = 0; j < 4; ++j)
    p += tanh(rp[j] + qv[j]) * (double)vw[l * 4 + j];
#pragma unroll
  for (int off = 32; off; off >>= 1) p += __shfl_xor(p, off);
  if (l == 0) out[w] = 10.0 * tanh(p + (double)vb[0]);
}

// ---------------------------------------------------------------------------
// q[r,:] = sum_s enc[r,s,:] * softmax(gl[r,:])[s]   (fp64)
// ---------------------------------------------------------------------------
__global__ __launch_bounds__(256) void softmax_wsum(
    const double* __restrict__ gl, const double* __restrict__ enc,
    double* __restrict__ q) {
  __shared__ double wgt[SS];
  __shared__ double red[256];
  int r = blockIdx.x, t = threadIdx.x;
  double x = (t < SS) ? gl[(size_t)r * SS + t] : -1e300;
  red[t] = x;
  __syncthreads();
  for (int st = 128; st; st >>= 1) {
    if (t < st) red[t] = fmax(red[t], red[t + st]);
    __syncthreads();
  }
  double mx = red[0];
  __syncthreads();
  double e = (t < SS) ? exp(x - mx) : 0.0;
  red[t] = e;
  __syncthreads();
  for (int st = 128; st; st >>= 1) {
    if (t < st) red[t] += red[t + st];
    __syncthreads();
  }
  double sum = red[0];
  if (t < SS) wgt[t] = e / sum;
  __syncthreads();

  const double* eb = enc + (size_t)r * (SS * HH);
  double acc = 0.0;
  for (int s = 0; s < SS; ++s) acc = fma(eb[s * HH + t], wgt[s], acc);
  q[(size_t)r * HH + t] = acc;
}

// ---------------------------------------------------------------------------
// Gumbel-argmax sampling (partitionable threefry), log_softmax, mask+dec_in.
// Chunk-local except: RNG index & output writes use global b = base + r.
// ---------------------------------------------------------------------------
__global__ __launch_bounds__(128) void sample_step(
    const double* __restrict__ pl, const float* __restrict__ inputs,
    const float* __restrict__ emb_w, const float* __restrict__ emb_b,
    double* __restrict__ dec_in, int* __restrict__ mask,
    float* __restrict__ out, int step, int base) {
  __shared__ double vals[128];
  __shared__ int    idxs[128];
  __shared__ double red[128];
  int r = blockIdx.x, t = threadIdx.x;
  int b = base + r;
  double x = (t < SS) ? pl[(size_t)r * SS + t] : -1e300;

  double val = -1e300;
  if (t < SS) {
    // partitionable split: child key k = threefry(key, (0, k)) output pair
    unsigned kk0, kk1;
    threefry2x32(0u, 42u, 0u, (unsigned)step, kk0, kk1);
    // partitionable 32-bit draw at flat j: bits = o0 ^ o1 at counter (0, j)
    unsigned j = (unsigned)(b * SS + t);
    unsigned o0, o1;
    threefry2x32(kk0, kk1, 0u, j, o0, o1);
    unsigned bits = o0 ^ o1;
    double u = (double)(bits >> 9) * 0x1p-23;   // exact f32 uniform value
    if (u == 0.0) u = 1.17549435e-38;           // max(f32 tiny, u)
    val = x + (-log(-log(u)));
  }
  vals[t] = val;
  idxs[t] = t;
  red[t] = x;
  __syncthreads();
  for (int st = 64; st; st >>= 1) {
    if (t < st) {
      double v1 = vals[t], v2 = vals[t + st];
      int i1 = idxs[t], i2 = idxs[t + st];
      if (v2 > v1 || (v2 == v1 && i2 < i1)) { vals[t] = v2; idxs[t] = i2; }
      red[t] = fmax(red[t], red[t + st]);
    }
    __syncthreads();
  }
  int chosen = idxs[0];
  double mx = red[0];
  __syncthreads();
  red[t] = (t < SS) ? exp(x - mx) : 0.0;
  __syncthreads();
  for (int st = 64; st; st >>= 1) {
    if (t < st) red[t] += red[t + st];
    __syncthreads();
  }
  if (t == 0) {
    double lse = log(red[0]);
    double xc = pl[(size_t)r * SS + chosen];
    out[(size_t)b * SS + step] = (float)(xc - mx - lse);            // lps
    out[(size_t)BB * SS + (size_t)b * SS + step] = (float)chosen;   // chs
    mask[r * SS + chosen] = 1;
  }
  __syncthreads();
  // dec_in = embedded[b, chosen, :]  (recomputed, fp64)
  int ib = (b * SS + chosen) * 2;
  double i0 = (double)inputs[ib], i1 = (double)inputs[ib + 1];
  for (int h = t; h < HH; h += 128) {
    dec_in[(size_t)r * HH + h] =
        i0 * (double)emb_w[2 * h] + i1 * (double)emb_w[2 * h + 1] + (double)emb_b[h];
  }
}

// Diagnostic: encode ws_size (MB) into output so absmax reveals it.
__global__ __launch_bounds__(256) void diag_kernel(float* __restrict__ out, float v) {
  int i = blockIdx.x * 256 + threadIdx.x;
  if (i < 2 * BB * SS) out[i] = v;
}

// ---------------------------------------------------------------------------
extern "C" void kernel_launch(void* const* d_in, const int* in_sizes, int n_in,
                              void* d_out, int out_size, void* d_ws, size_t ws_size,
                              hipStream_t stream) {
  (void)in_sizes; (void)n_in; (void)out_size;
  const float* inputs    = (const float*)d_in[0];
  const float* emb_w     = (const float*)d_in[1];
  const float* emb_b     = (const float*)d_in[2];
  const float* enc_wih   = (const float*)d_in[3];
  const float* enc_whh   = (const float*)d_in[4];
  const float* enc_bih   = (const float*)d_in[5];
  const float* enc_bhh   = (const float*)d_in[6];
  const float* dec_wih   = (const float*)d_in[7];
  const float* dec_whh   = (const float*)d_in[8];
  const float* dec_bih   = (const float*)d_in[9];
  const float* dec_bhh   = (const float*)d_in[10];
  const float* ptr_wq_w  = (const float*)d_in[11];
  const float* ptr_wq_b  = (const float*)d_in[12];
  const float* ptr_wref_w= (const float*)d_in[13];
  const float* ptr_wref_b= (const float*)d_in[14];
  const float* ptr_v_w   = (const float*)d_in[15];
  const float* ptr_v_b   = (const float*)d_in[16];
  const float* glm_wq_w  = (const float*)d_in[17];
  const float* glm_wq_b  = (const float*)d_in[18];
  const float* glm_wref_w= (const float*)d_in[19];
  const float* glm_wref_b= (const float*)d_in[20];
  const float* glm_v_w   = (const float*)d_in[21];
  const float* glm_v_b   = (const float*)d_in[22];
  const float* start     = (const float*)d_in[23];
  float* out = (float*)d_out;

  // ---- workspace layout (sized for CMAX = 384 rows), all fp64 ----
  char* base_p = (char*)d_ws;
  size_t off = 0;
  auto take = [&](size_t nbytes) {
    void* p = base_p + off;
    off = (off + nbytes + 255) & ~(size_t)255;
    return p;
  };
  const size_t BIGC = (size_t)CMAX * SS * HH;            // 9,830,400 elems
  double* enc_c  = (double*)take(BIGC * 8);              // 78.6 MB
  double* ref_g  = (double*)take(BIGC * 8);              // 78.6 MB
  double* ref_p  = (double*)take(BIGC * 8);              // 78.6 MB
  double* hbuf   = (double*)take((size_t)CMAX * HH * 8);
  double* cbuf   = (double*)take((size_t)CMAX * HH * 8);
  double* dec_in = (double*)take((size_t)CMAX * HH * 8);
  double* xslice = (double*)take((size_t)CMAX * HH * 8);
  double* qg     = (double*)take((size_t)CMAX * HH * 8);
  double* qp     = (double*)take((size_t)CMAX * HH * 8);
  double* qbuf   = (double*)take((size_t)CMAX * HH * 8);
  double* gates  = (double*)take((size_t)CMAX * 4 * HH * 8);
  double* gl     = (double*)take((size_t)CMAX * SS * 8);
  double* pl     = (double*)take((size_t)CMAX * SS * 8);
  int*    mask   = (int*)take((size_t)CMAX * SS * 4);

  if (ws_size < off) {  // ~246 MB needed; diag-encode ws_size if short
    diag_kernel<<<(2 * BB * SS + 255) / 256, 256, 0, stream>>>(
        out, (float)(ws_size >> 20));
    return;
  }

  for (int cb = 0; cb < BB; cb += CMAX) {
    const int M = (BB - cb < CMAX) ? (BB - cb) : CMAX;   // 384, 384, 256
    const int MT = M / 64;                                // gemm tiles in M

    // ---- encoder (chunk rows, fp64 state) ----
    zero_hc<<<M, 256, 0, stream>>>(hbuf, cbuf);
    for (int t = 0; t < SS; ++t) {
      embed_slice<<<M, 256, 0, stream>>>(inputs, emb_w, emb_b, xslice, t, cb);
      gemm_dual<<<dim3(MT, 16), 256, 0, stream>>>(
          xslice, HH, enc_wih, HH, hbuf, HH, enc_whh, HH,
          enc_bih, enc_bhh, gates, 4 * HH);
      lstm_update<<<M, 256, 0, stream>>>(gates, hbuf, cbuf, enc_c + (size_t)t * HH);
    }

    // ---- ref projections (M*S rows) ----
    gemm_dual<<<dim3(M * SS / 64, 4), 256, 0, stream>>>(
        enc_c, HH, glm_wref_w, HH, nullptr, 0, nullptr, 0,
        glm_wref_b, nullptr, ref_g, HH);
    gemm_dual<<<dim3(M * SS / 64, 4), 256, 0, stream>>>(
        enc_c, HH, ptr_wref_w, HH, nullptr, 0, nullptr, 0,
        ptr_wref_b, nullptr, ref_p, HH);

    // ---- decoder (h,c carry over from encoder in hbuf/cbuf) ----
    init_dec<<<M, 256, 0, stream>>>(dec_in, mask, start);
    for (int k = 0; k < SS; ++k) {
      gemm_dual<<<dim3(MT, 16), 256, 0, stream>>>(
          dec_in, HH, dec_wih, HH, hbuf, HH, dec_whh, HH,
          dec_bih, dec_bhh, gates, 4 * HH);
      lstm_update<<<M, 256, 0, stream>>>(gates, hbuf, cbuf, nullptr);
      gemm_dual<<<dim3(MT, 4), 256, 0, stream>>>(
          hbuf, HH, glm_wq_w, HH, nullptr, 0, nullptr, 0,
          glm_wq_b, nullptr, qg, HH);
      attn_logits<<<M * SS / 4, 256, 0, stream>>>(ref_g, qg, glm_v_w, glm_v_b, mask, gl);
      softmax_wsum<<<M, 256, 0, stream>>>(gl, enc_c, qbuf);
      gemm_dual<<<dim3(MT, 4), 256, 0, stream>>>(
          qbuf, HH, ptr_wq_w, HH, nullptr, 0, nullptr, 0,
          ptr_wq_b, nullptr, qp, HH);
      attn_logits<<<M * SS / 4, 256, 0, stream>>>(ref_p, qp, ptr_v_w, ptr_v_b, mask, pl);
      sample_step<<<M, 128, 0, stream>>>(pl, inputs, emb_w, emb_b, dec_in, mask, out, k, cb);
    }
  }
}

// Round 4
// 44287.491 us; speedup vs baseline: 1.7954x; 1.7954x over previous
//
#include <hip/hip_runtime.h>
#include <cstdint>
#include <cstddef>

#define BB 1024
#define SS 100
#define HH 256
#define CH 512   // batch chunk rows (2 chunks)

// ---------------------------------------------------------------------------
// Bit-exact JAX threefry2x32 (partitionable mode — verified round 3)
// ---------------------------------------------------------------------------
__device__ __forceinline__ unsigned rotl32(unsigned v, int r) {
  return (v << r) | (v >> (32 - r));
}

__device__ __forceinline__ void threefry2x32(unsigned k0, unsigned k1,
                                             unsigned x0, unsigned x1,
                                             unsigned& o0, unsigned& o1) {
  unsigned k2 = k0 ^ k1 ^ 0x1BD11BDAu;
  x0 += k0; x1 += k1;
#define TF_R(r) { x0 += x1; x1 = rotl32(x1, (r)); x1 ^= x0; }
  TF_R(13) TF_R(15) TF_R(26) TF_R(6)
  x0 += k1; x1 += k2 + 1u;
  TF_R(17) TF_R(29) TF_R(16) TF_R(24)
  x0 += k2; x1 += k0 + 2u;
  TF_R(13) TF_R(15) TF_R(26) TF_R(6)
  x0 += k0; x1 += k1 + 3u;
  TF_R(17) TF_R(29) TF_R(16) TF_R(24)
  x0 += k1; x1 += k2 + 4u;
  TF_R(13) TF_R(15) TF_R(26) TF_R(6)
  x0 += k2; x1 += k0 + 5u;
#undef TF_R
  o0 = x0; o1 = x1;
}

__device__ __forceinline__ double sigd(double x) {
  return 1.0 / (1.0 + exp(-x));
}

// ---------------------------------------------------------------------------
__global__ __launch_bounds__(256) void init_chunk(
    double* __restrict__ h, double* __restrict__ c) {
  int i = blockIdx.x * 256 + threadIdx.x;
  h[i] = 0.0;
  c[i] = 0.0;
}

__global__ __launch_bounds__(256) void init_dec(
    double* __restrict__ dec_in, int* __restrict__ mask,
    const float* __restrict__ start) {
  int r = blockIdx.x, t = threadIdx.x;
  dec_in[r * HH + t] = (double)start[t];
  if (t < SS) mask[r * SS + t] = 0;
}

// WqT[k,t] = Wq[t,k] for the two 256x256 query-projection matrices
__global__ __launch_bounds__(256) void transpose2(
    const float* __restrict__ a, const float* __restrict__ b,
    float* __restrict__ at, float* __restrict__ bt) {
  int k = blockIdx.x, t = threadIdx.x;
  at[k * HH + t] = a[t * HH + k];
  bt[k * HH + t] = b[t * HH + k];
}

// ---------------------------------------------------------------------------
// Fused LSTM step: gates = A@Wih^T + bih + h@Whh^T + bhh ; LSTM nonlinearity
// in-register; writes h,c (and optional enc_c fp32 slice).
// A = embed(inputs[:,t,:]) computed on the fly (EMBED) or dec_in (fp64).
// Tile: 32 rows x 16 u-cols x 4 gates. Thread: 2 rows x 4 gates of one u.
// Grid: (CH/32, 16). All math fp64.
// ---------------------------------------------------------------------------
template <bool EMBED>
__global__ __launch_bounds__(256) void lstm_gates(
    const float* __restrict__ inputs, const float* __restrict__ emb_w,
    const float* __restrict__ emb_b, int t, int cb,
    const double* __restrict__ dec_in,
    const float* __restrict__ Wih, const float* __restrict__ Whh,
    const float* __restrict__ bih, const float* __restrict__ bhh,
    double* __restrict__ h, double* __restrict__ c,
    float* __restrict__ enc_c) {
  __shared__ double As[16][34];
  __shared__ double Ws[16][66];
  const int tid = threadIdx.x;
  const int tx = tid & 15;          // u within block
  const int ty = tid >> 4;          // row pair
  const int m0 = blockIdx.x * 32;
  const int u0 = blockIdx.y * 16;
  // staging roles
  const int arow = tid >> 3;              // 0..31
  const int acol = (tid & 7) * 2;         // 0,2,..,14
  const int wn   = tid >> 2;              // 0..63  (n_local = gate*16+u_loc)
  const int wcol = (tid & 3) * 4;         // 0,4,8,12
  const int wgate = wn >> 4, wu = wn & 15;
  double acc[2][4] = {};

  // hoisted embed inputs for this thread's staging row
  double in0 = 0.0, in1 = 0.0;
  if (EMBED) {
    int b = cb + m0 + arow;
    in0 = (double)inputs[(b * SS + t) * 2];
    in1 = (double)inputs[(b * SS + t) * 2 + 1];
  }

  for (int ph = 0; ph < 2; ++ph) {
    const float* W = ph ? Whh : Wih;
    const float* wrow = W + (size_t)(wgate * HH + u0 + wu) * HH;
    for (int k0 = 0; k0 < HH; k0 += 16) {
      double a0, a1;
      if (ph == 0) {
        if (EMBED) {
          int k = k0 + acol;
          a0 = in0 * (double)emb_w[2 * k] + in1 * (double)emb_w[2 * k + 1] +
               (double)emb_b[k];
          a1 = in0 * (double)emb_w[2 * k + 2] + in1 * (double)emb_w[2 * k + 3] +
               (double)emb_b[k + 1];
        } else {
          const double* ar = dec_in + (size_t)(m0 + arow) * HH + k0 + acol;
          a0 = ar[0]; a1 = ar[1];
        }
      } else {
        const double* ar = h + (size_t)(m0 + arow) * HH + k0 + acol;
        a0 = ar[0]; a1 = ar[1];
      }
      float4 wv = *(const float4*)(wrow + k0 + wcol);
      __syncthreads();
      As[acol][arow] = a0;
      As[acol + 1][arow] = a1;
      Ws[wcol + 0][wn] = (double)wv.x;
      Ws[wcol + 1][wn] = (double)wv.y;
      Ws[wcol + 2][wn] = (double)wv.z;
      Ws[wcol + 3][wn] = (double)wv.w;
      __syncthreads();
#pragma unroll
      for (int kk = 0; kk < 16; ++kk) {
        double a0k = As[kk][ty * 2];
        double a1k = As[kk][ty * 2 + 1];
#pragma unroll
        for (int j = 0; j < 4; ++j) {
          double w = Ws[kk][j * 16 + tx];
          acc[0][j] = fma(a0k, w, acc[0][j]);
          acc[1][j] = fma(a1k, w, acc[1][j]);
        }
      }
    }
  }

  const int u = u0 + tx;
#pragma unroll
  for (int i = 0; i < 2; ++i) {
    int r = m0 + ty * 2 + i;
    double gi = acc[i][0] + (double)bih[u] + (double)bhh[u];
    double gf = acc[i][1] + (double)bih[HH + u] + (double)bhh[HH + u];
    double gg = acc[i][2] + (double)bih[2 * HH + u] + (double)bhh[2 * HH + u];
    double go = acc[i][3] + (double)bih[3 * HH + u] + (double)bhh[3 * HH + u];
    size_t idx = (size_t)r * HH + u;
    double cp = c[idx];
    double cn = sigd(gf) * cp + sigd(gi) * tanh(gg);
    double hn = sigd(go) * tanh(cn);
    c[idx] = cn;
    h[idx] = hn;
    if (enc_c) enc_c[((size_t)r * SS + t) * HH + u] = (float)hn;
  }
}

// ---------------------------------------------------------------------------
// Ref projection: C[m,n] = sum_k A[m,k]*W[n,k] + b[n]; A,C fp32, math fp64.
// Tile 64x64, thread 4x4, K=256.
// ---------------------------------------------------------------------------
__global__ __launch_bounds__(256) void proj_gemm(
    const float* __restrict__ A, const float* __restrict__ W,
    const float* __restrict__ bias, float* __restrict__ C) {
  __shared__ double As[16][68];
  __shared__ double Ws[16][68];
  const int tid = threadIdx.x;
  const int tx = tid & 15, ty = tid >> 4;
  const int m0 = blockIdx.x * 64;
  const int n0 = blockIdx.y * 64;
  const int lrow = tid >> 2;
  const int lcol = (tid & 3) << 2;
  double acc[4][4] = {};

  const float* ar = A + (size_t)(m0 + lrow) * HH;
  const float* wr = W + (size_t)(n0 + lrow) * HH;
  for (int k0 = 0; k0 < HH; k0 += 16) {
    float4 av = *(const float4*)(ar + k0 + lcol);
    float4 wv = *(const float4*)(wr + k0 + lcol);
    __syncthreads();
    As[lcol + 0][lrow] = (double)av.x; As[lcol + 1][lrow] = (double)av.y;
    As[lcol + 2][lrow] = (double)av.z; As[lcol + 3][lrow] = (double)av.w;
    Ws[lcol + 0][lrow] = (double)wv.x; Ws[lcol + 1][lrow] = (double)wv.y;
    Ws[lcol + 2][lrow] = (double)wv.z; Ws[lcol + 3][lrow] = (double)wv.w;
    __syncthreads();
#pragma unroll
    for (int kk = 0; kk < 16; ++kk) {
      double a[4], w[4];
#pragma unroll
      for (int i = 0; i < 4; ++i) a[i] = As[kk][ty * 4 + i];
#pragma unroll
      for (int j = 0; j < 4; ++j) w[j] = Ws[kk][tx * 4 + j];
#pragma unroll
      for (int i = 0; i < 4; ++i)
#pragma unroll
        for (int j = 0; j < 4; ++j) acc[i][j] = fma(a[i], w[j], acc[i][j]);
    }
  }
#pragma unroll
  for (int i = 0; i < 4; ++i) {
    float* crow = C + (size_t)(m0 + ty * 4 + i) * HH + n0 + tx * 4;
#pragma unroll
    for (int j = 0; j < 4; ++j)
      crow[j] = (float)(acc[i][j] + (double)bias[n0 + tx * 4 + j]);
  }
}

// ---------------------------------------------------------------------------
// Fused decoder attention + sampling, one block per batch row r.
//   qg = h@Wq_g^T + b; gl[s] = attn(ref_g, qg); wgt = softmax(gl);
//   q  = sum_s enc[s]*wgt[s]; qp = q@Wq_p^T + b; pl[s] = attn(ref_p, qp);
//   gumbel-argmax sample; lps/chs outputs; mask, dec_in update.
// All math fp64; big tensors stored fp32; Wq pre-transposed for coalescing.
// ---------------------------------------------------------------------------
__global__ __launch_bounds__(256) void dec_attn_sample(
    const double* __restrict__ h,
    const float* __restrict__ enc_c, const float* __restrict__ ref_g,
    const float* __restrict__ ref_p,
    const float* __restrict__ wqt_g, const float* __restrict__ bq_g,
    const float* __restrict__ vw_g, const float* __restrict__ vb_g,
    const float* __restrict__ wqt_p, const float* __restrict__ bq_p,
    const float* __restrict__ vw_p, const float* __restrict__ vb_p,
    int* __restrict__ mask, double* __restrict__ dec_in,
    const float* __restrict__ inputs, const float* __restrict__ emb_w,
    const float* __restrict__ emb_b,
    float* __restrict__ out, int step, int cb) {
  __shared__ double hq[HH];     // h row, then glimpse q row
  __shared__ double qv[HH];     // projected query
  __shared__ double lg[SS];     // logits, then softmax weights
  __shared__ double red[256];
  __shared__ int    ridx[256];
  __shared__ int    sh_chosen;

  const int r = blockIdx.x, t = threadIdx.x;
  const int w = t >> 6, l = t & 63;
  const int b = cb + r;

  hq[t] = h[(size_t)r * HH + t];
  __syncthreads();

  // ---- glimpse query projection ----
  {
    double acc = 0.0;
#pragma unroll 4
    for (int k = 0; k < HH; ++k)
      acc = fma((double)wqt_g[k * HH + t], hq[k], acc);
    qv[t] = acc + (double)bq_g[t];
  }
  __syncthreads();

  // ---- glimpse logits ----
  for (int s = w; s < SS; s += 4) {
    if (mask[r * SS + s]) {
      if (l == 0) lg[s] = -10.0;
      continue;
    }
    const float* rp = ref_g + ((size_t)r * SS + s) * HH + l * 4;
    double p = 0.0;
#pragma unroll
    for (int j = 0; j < 4; ++j)
      p += tanh((double)rp[j] + qv[l * 4 + j]) * (double)vw_g[l * 4 + j];
#pragma unroll
    for (int off = 32; off; off >>= 1) p += __shfl_xor(p, off);
    if (l == 0) lg[s] = 10.0 * tanh(p + (double)vb_g[0]);
  }
  __syncthreads();

  // ---- softmax over gl -> weights in lg ----
  {
    double x = (t < SS) ? lg[t] : -1e300;
    red[t] = x;
    __syncthreads();
    for (int st = 128; st; st >>= 1) {
      if (t < st) red[t] = fmax(red[t], red[t + st]);
      __syncthreads();
    }
    double mx = red[0];
    __syncthreads();
    double e = (t < SS) ? exp(x - mx) : 0.0;
    red[t] = e;
    __syncthreads();
    for (int st = 128; st; st >>= 1) {
      if (t < st) red[t] += red[t + st];
      __syncthreads();
    }
    double sum = red[0];
    __syncthreads();
    if (t < SS) lg[t] = e / sum;
  }
  __syncthreads();

  // ---- weighted sum of enc -> glimpse q (into hq) ----
  {
    const float* eb = enc_c + (size_t)r * SS * HH + t;
    double acc = 0.0;
    for (int s = 0; s < SS; ++s) acc = fma((double)eb[s * HH], lg[s], acc);
    __syncthreads();
    hq[t] = acc;
  }
  __syncthreads();

  // ---- pointer query projection ----
  {
    double acc = 0.0;
#pragma unroll 4
    for (int k = 0; k < HH; ++k)
      acc = fma((double)wqt_p[k * HH + t], hq[k], acc);
    qv[t] = acc + (double)bq_p[t];
  }
  __syncthreads();

  // ---- pointer logits ----
  for (int s = w; s < SS; s += 4) {
    if (mask[r * SS + s]) {
      if (l == 0) lg[s] = -10.0;
      continue;
    }
    const float* rp = ref_p + ((size_t)r * SS + s) * HH + l * 4;
    double p = 0.0;
#pragma unroll
    for (int j = 0; j < 4; ++j)
      p += tanh((double)rp[j] + qv[l * 4 + j]) * (double)vw_p[l * 4 + j];
#pragma unroll
    for (int off = 32; off; off >>= 1) p += __shfl_xor(p, off);
    if (l == 0) lg[s] = 10.0 * tanh(p + (double)vb_p[0]);
  }
  __syncthreads();

  // ---- gumbel-argmax (partitionable threefry, exact round-3 recipe) ----
  double x = (t < SS) ? lg[t] : -1e300;
  double val = -1e300;
  if (t < SS) {
    unsigned kk0, kk1;
    threefry2x32(0u, 42u, 0u, (unsigned)step, kk0, kk1);
    unsigned j = (unsigned)(b * SS + t);
    unsigned o0, o1;
    threefry2x32(kk0, kk1, 0u, j, o0, o1);
    unsigned bits = o0 ^ o1;
    double u = (double)(bits >> 9) * 0x1p-23;
    if (u == 0.0) u = 1.17549435e-38;
    val = x + (-log(-log(u)));
  }
  red[t] = val;
  ridx[t] = t;
  __syncthreads();
  for (int st = 128; st; st >>= 1) {
    if (t < st) {
      double v1 = red[t], v2 = red[t + st];
      int i1 = ridx[t], i2 = ridx[t + st];
      if (v2 > v1 || (v2 == v1 && i2 < i1)) { red[t] = v2; ridx[t] = i2; }
    }
    __syncthreads();
  }
  if (t == 0) sh_chosen = ridx[0];
  __syncthreads();
  int chosen = sh_chosen;

  // ---- log-softmax pieces ----
  red[t] = x;
  __syncthreads();
  for (int st = 128; st; st >>= 1) {
    if (t < st) red[t] = fmax(red[t], red[t + st]);
    __syncthreads();
  }
  double mx = red[0];
  __syncthreads();
  red[t] = (t < SS) ? exp(x - mx) : 0.0;
  __syncthreads();
  for (int st = 128; st; st >>= 1) {
    if (t < st) red[t] += red[t + st];
    __syncthreads();
  }
  if (t == 0) {
    double lse = log(red[0]);
    double xc = lg[chosen];
    out[(size_t)b * SS + step] = (float)(xc - mx - lse);            // lps
    out[(size_t)BB * SS + (size_t)b * SS + step] = (float)chosen;   // chs
    mask[r * SS + chosen] = 1;
  }
  __syncthreads();

  // ---- dec_in = embedded[b, chosen, :] (fp64 recompute) ----
  int ib = (b * SS + chosen) * 2;
  double i0 = (double)inputs[ib], i1 = (double)inputs[ib + 1];
  dec_in[(size_t)r * HH + t] =
      i0 * (double)emb_w[2 * t] + i1 * (double)emb_w[2 * t + 1] + (double)emb_b[t];
}

// Diagnostic: encode ws_size (MB) into output so absmax reveals it.
__global__ __launch_bounds__(256) void diag_kernel(float* __restrict__ out, float v) {
  int i = blockIdx.x * 256 + threadIdx.x;
  if (i < 2 * BB * SS) out[i] = v;
}

// ---------------------------------------------------------------------------
extern "C" void kernel_launch(void* const* d_in, const int* in_sizes, int n_in,
                              void* d_out, int out_size, void* d_ws, size_t ws_size,
                              hipStream_t stream) {
  (void)in_sizes; (void)n_in; (void)out_size;
  const float* inputs    = (const float*)d_in[0];
  const float* emb_w     = (const float*)d_in[1];
  const float* emb_b     = (const float*)d_in[2];
  const float* enc_wih   = (const float*)d_in[3];
  const float* enc_whh   = (const float*)d_in[4];
  const float* enc_bih   = (const float*)d_in[5];
  const float* enc_bhh   = (const float*)d_in[6];
  const float* dec_wih   = (const float*)d_in[7];
  const float* dec_whh   = (const float*)d_in[8];
  const float* dec_bih   = (const float*)d_in[9];
  const float* dec_bhh   = (const float*)d_in[10];
  const float* ptr_wq_w  = (const float*)d_in[11];
  const float* ptr_wq_b  = (const float*)d_in[12];
  const float* ptr_wref_w= (const float*)d_in[13];
  const float* ptr_wref_b= (const float*)d_in[14];
  const float* ptr_v_w   = (const float*)d_in[15];
  const float* ptr_v_b   = (const float*)d_in[16];
  const float* glm_wq_w  = (const float*)d_in[17];
  const float* glm_wq_b  = (const float*)d_in[18];
  const float* glm_wref_w= (const float*)d_in[19];
  const float* glm_wref_b= (const float*)d_in[20];
  const float* glm_v_w   = (const float*)d_in[21];
  const float* glm_v_b   = (const float*)d_in[22];
  const float* start     = (const float*)d_in[23];
  float* out = (float*)d_out;

  char* base_p = (char*)d_ws;
  size_t off = 0;
  auto take = [&](size_t nbytes) {
    void* p = base_p + off;
    off = (off + nbytes + 255) & ~(size_t)255;
    return p;
  };
  const size_t BIGC = (size_t)CH * SS * HH;           // 13,107,200 elems
  float*  enc_c  = (float*)take(BIGC * 4);            // 52.4 MB
  float*  ref_g  = (float*)take(BIGC * 4);            // 52.4 MB
  float*  ref_p  = (float*)take(BIGC * 4);            // 52.4 MB
  double* hbuf   = (double*)take((size_t)CH * HH * 8);
  double* cbuf   = (double*)take((size_t)CH * HH * 8);
  double* dec_in = (double*)take((size_t)CH * HH * 8);
  int*    mask   = (int*)take((size_t)CH * SS * 4);
  float*  wqt_g  = (float*)take((size_t)HH * HH * 4);
  float*  wqt_p  = (float*)take((size_t)HH * HH * 4);

  if (ws_size < off) {
    diag_kernel<<<(2 * BB * SS + 255) / 256, 256, 0, stream>>>(
        out, (float)(ws_size >> 20));
    return;
  }

  transpose2<<<HH, HH, 0, stream>>>(glm_wq_w, ptr_wq_w, wqt_g, wqt_p);

  for (int cb = 0; cb < BB; cb += CH) {
    // ---- encoder ----
    init_chunk<<<CH, 256, 0, stream>>>(hbuf, cbuf);
    for (int t = 0; t < SS; ++t) {
      lstm_gates<true><<<dim3(CH / 32, 16), 256, 0, stream>>>(
          inputs, emb_w, emb_b, t, cb, nullptr,
          enc_wih, enc_whh, enc_bih, enc_bhh, hbuf, cbuf, enc_c);
    }

    // ---- ref projections (CH*SS rows) ----
    proj_gemm<<<dim3(CH * SS / 64, 4), 256, 0, stream>>>(
        enc_c, glm_wref_w, glm_wref_b, ref_g);
    proj_gemm<<<dim3(CH * SS / 64, 4), 256, 0, stream>>>(
        enc_c, ptr_wref_w, ptr_wref_b, ref_p);

    // ---- decoder ----
    init_dec<<<CH, 256, 0, stream>>>(dec_in, mask, start);
    for (int k = 0; k < SS; ++k) {
      lstm_gates<false><<<dim3(CH / 32, 16), 256, 0, stream>>>(
          inputs, emb_w, emb_b, 0, cb, dec_in,
          dec_wih, dec_whh, dec_bih, dec_bhh, hbuf, cbuf, nullptr);
      dec_attn_sample<<<CH, 256, 0, stream>>>(
          hbuf, enc_c, ref_g, ref_p,
          wqt_g, glm_wq_b, glm_v_w, glm_v_b,
          wqt_p, ptr_wq_b, ptr_v_w, ptr_v_b,
          mask, dec_in, inputs, emb_w, emb_b, out, k, cb);
    }
  }
}